// Round 1
// baseline (2745.227 us; speedup 1.0000x reference)
//
#include <hip/hip_runtime.h>

#define DIM 64

// ---------------- edge dtype detection + conversion ----------------
// JAX without x64 turns the declared int64 edge_index into int32. Detect on
// device: if the buffer is int64, every odd 32-bit word (high half) is 0.
// For int32 data those words are random node ids in [0,150000) -> P(all 8
// zero) ~ 0.
__device__ __forceinline__ bool edges_are_i64(const unsigned int* w) {
    unsigned int acc = 0;
#pragma unroll
    for (int k = 0; k < 8; ++k) acc |= w[2 * k + 1];
    return acc == 0;
}

__global__ void k_convert(const void* ei_raw, int* edges, int n2) {
    int i = blockIdx.x * blockDim.x + threadIdx.x;
    if (i >= n2) return;
    const unsigned int* w = (const unsigned int*)ei_raw;
    bool is64 = edges_are_i64(w);
    int v = is64 ? (int)(((const long long*)ei_raw)[i]) : ((const int*)ei_raw)[i];
    edges[i] = v;
}

// ---------------- degree / norm ----------------
__global__ void k_deg(const int* __restrict__ dst, int* __restrict__ deg, int E) {
    int e = blockIdx.x * blockDim.x + threadIdx.x;
    if (e < E) atomicAdd(&deg[dst[e]], 1);
}

__global__ void k_dinv(const int* __restrict__ deg, float* __restrict__ dinv, int N) {
    int n = blockIdx.x * blockDim.x + threadIdx.x;
    if (n < N) {
        int d = deg[n];
        dinv[n] = d > 0 ? 1.0f / sqrtf((float)d) : 0.0f;
    }
}

__global__ void k_norm(const int* __restrict__ edges, const float* __restrict__ dinv,
                       float* __restrict__ norm, int E) {
    int e = blockIdx.x * blockDim.x + threadIdx.x;
    if (e < E) norm[e] = dinv[edges[e]] * dinv[edges[E + e]];
}

// ---------------- out = alpha[aidx] * x  (float4) ----------------
__global__ void k_scale(const float* __restrict__ x, const float* __restrict__ alpha,
                        int aidx, float* __restrict__ out, int n4) {
    int i = blockIdx.x * blockDim.x + threadIdx.x;
    if (i >= n4) return;
    float a = alpha[aidx];
    float4 v = ((const float4*)x)[i];
    float4 o;
    o.x = a * v.x; o.y = a * v.y; o.z = a * v.z; o.w = a * v.w;
    ((float4*)out)[i] = o;
}

// ---------------- scatter: xnext[dst] += norm[e] * xsrc[src] ----------------
// 16 threads per edge, float4 each (64 floats/row).
__global__ void k_scatter(const int* __restrict__ edges, const float* __restrict__ norm,
                          const float* __restrict__ xsrc, float* __restrict__ xnext, int E) {
    int t = blockIdx.x * blockDim.x + threadIdx.x;
    int e = t >> 4, c = t & 15;
    if (e >= E) return;
    int s = edges[e];
    int d = edges[E + e];
    float w = norm[e];
    float4 v = ((const float4*)(xsrc + (size_t)s * DIM))[c];
    float* p = xnext + (size_t)d * DIM + c * 4;
    unsafeAtomicAdd(p + 0, w * v.x);
    unsafeAtomicAdd(p + 1, w * v.y);
    unsafeAtomicAdd(p + 2, w * v.z);
    unsafeAtomicAdd(p + 3, w * v.w);
}

// ---------------- out += alpha[aidx] * x  (float4) ----------------
__global__ void k_accum(float* __restrict__ out, const float* __restrict__ x,
                        const float* __restrict__ alpha, int aidx, int n4) {
    int i = blockIdx.x * blockDim.x + threadIdx.x;
    if (i >= n4) return;
    float a = alpha[aidx];
    float4 v = ((const float4*)x)[i];
    float4 o = ((float4*)out)[i];
    o.x += a * v.x; o.y += a * v.y; o.z += a * v.z; o.w += a * v.w;
    ((float4*)out)[i] = o;
}

// ---------------- final: res[e] = dot(out[src], out[dst]) ----------------
// 16 threads per edge, float4 partial dot, shuffle-reduce within 16 lanes.
__global__ void k_final(const int* __restrict__ edges, const float* __restrict__ out,
                        float* __restrict__ res, int E) {
    int t = blockIdx.x * blockDim.x + threadIdx.x;
    int e = t >> 4, c = t & 15;
    if (e >= E) return;
    int s = edges[e];
    int d = edges[E + e];
    float4 a = ((const float4*)(out + (size_t)s * DIM))[c];
    float4 b = ((const float4*)(out + (size_t)d * DIM))[c];
    float p = a.x * b.x + a.y * b.y + a.z * b.z + a.w * b.w;
    p += __shfl_down(p, 8, 16);
    p += __shfl_down(p, 4, 16);
    p += __shfl_down(p, 2, 16);
    p += __shfl_down(p, 1, 16);
    if (c == 0) res[e] = p;
}

static inline size_t alignUp(size_t x) { return (x + 511) & ~size_t(511); }

extern "C" void kernel_launch(void* const* d_in, const int* in_sizes, int n_in,
                              void* d_out, int out_size, void* d_ws, size_t ws_size,
                              hipStream_t stream) {
    const void*  ei    = d_in[0];
    const float* emb   = (const float*)d_in[1];
    const float* alpha = (const float*)d_in[2];
    float*       res   = (float*)d_out;

    const int E = in_sizes[0] / 2;       // 1,000,000
    const int N = in_sizes[1] / DIM;     // 150,000
    const int NUM_LAYERS = 3;

    // ---- carve workspace ----
    char* w = (char*)d_ws;
    size_t off = 0;
    int* edges = (int*)(w + off);   off = alignUp(off + (size_t)2 * E * sizeof(int));
    int* deg   = (int*)(w + off);   off = alignUp(off + (size_t)N * sizeof(int));
    float* dinv = (float*)(w + off); off = alignUp(off + (size_t)N * sizeof(float));
    float* norm = (float*)(w + off); off = alignUp(off + (size_t)E * sizeof(float));
    float* outv = (float*)(w + off); off = alignUp(off + (size_t)N * DIM * sizeof(float));
    float* xA   = (float*)(w + off); off = alignUp(off + (size_t)N * DIM * sizeof(float));
    float* xB   = (float*)(w + off); off = alignUp(off + (size_t)N * DIM * sizeof(float));
    (void)ws_size;

    const int B = 256;
    const int n2 = 2 * E;
    const int n4 = N * DIM / 4;

    hipMemsetAsync(deg, 0, (size_t)N * sizeof(int), stream);
    k_convert<<<(n2 + B - 1) / B, B, 0, stream>>>(ei, edges, n2);
    k_deg<<<(E + B - 1) / B, B, 0, stream>>>(edges + E, deg, E);
    k_dinv<<<(N + B - 1) / B, B, 0, stream>>>(deg, dinv, N);
    k_norm<<<(E + B - 1) / B, B, 0, stream>>>(edges, dinv, norm, E);

    // out = alpha[0] * emb
    k_scale<<<(n4 + B - 1) / B, B, 0, stream>>>(emb, alpha, 0, outv, n4);

    const float* xc = emb;
    float* bufs[2] = {xA, xB};
    for (int i = 0; i < NUM_LAYERS; ++i) {
        float* xn = bufs[i & 1];
        hipMemsetAsync(xn, 0, (size_t)N * DIM * sizeof(float), stream);
        long long t16 = (long long)E * 16;
        k_scatter<<<(int)((t16 + B - 1) / B), B, 0, stream>>>(edges, norm, xc, xn, E);
        k_accum<<<(n4 + B - 1) / B, B, 0, stream>>>(outv, xn, alpha, i + 1, n4);
        xc = xn;
    }

    long long t16 = (long long)E * 16;
    k_final<<<(int)((t16 + B - 1) / B), B, 0, stream>>>(edges, outv, res, E);
}

// Round 2
// 358.544 us; speedup vs baseline: 7.6566x; 7.6566x over previous
//
#include <hip/hip_runtime.h>

#define DIM 64

// ---------------- edge dtype detection + conversion ----------------
__device__ __forceinline__ bool edges_are_i64(const unsigned int* w) {
    unsigned int acc = 0;
#pragma unroll
    for (int k = 0; k < 8; ++k) acc |= w[2 * k + 1];
    return acc == 0;
}

__global__ void k_convert(const void* ei_raw, int* edges, int n2) {
    int i = blockIdx.x * blockDim.x + threadIdx.x;
    if (i >= n2) return;
    const unsigned int* w = (const unsigned int*)ei_raw;
    bool is64 = edges_are_i64(w);
    int v = is64 ? (int)(((const long long*)ei_raw)[i]) : ((const int*)ei_raw)[i];
    edges[i] = v;
}

// ---------------- degree ----------------
__global__ void k_deg(const int* __restrict__ dst, int* __restrict__ deg, int E) {
    int e = blockIdx.x * blockDim.x + threadIdx.x;
    if (e < E) atomicAdd(&deg[dst[e]], 1);
}

__global__ void k_dinv(const int* __restrict__ deg, float* __restrict__ dinv, int N) {
    int n = blockIdx.x * blockDim.x + threadIdx.x;
    if (n < N) {
        int d = deg[n];
        dinv[n] = d > 0 ? 1.0f / sqrtf((float)d) : 0.0f;
    }
}

// ---------------- exclusive scan of deg -> rowptr ----------------
// scan1: per-block (256) exclusive scan + block sums
__global__ void k_scan1(const int* __restrict__ deg, int* __restrict__ rowptr,
                        int* __restrict__ bsum, int N) {
    __shared__ int sh[256];
    int i = blockIdx.x * 256 + threadIdx.x;
    int v = (i < N) ? deg[i] : 0;
    sh[threadIdx.x] = v;
    __syncthreads();
    for (int o = 1; o < 256; o <<= 1) {
        int t = (threadIdx.x >= o) ? sh[threadIdx.x - o] : 0;
        __syncthreads();
        sh[threadIdx.x] += t;
        __syncthreads();
    }
    if (i < N) rowptr[i] = sh[threadIdx.x] - v;  // exclusive
    if (threadIdx.x == 255) bsum[blockIdx.x] = sh[255];
}

// scan2: single block (1024) exclusive scan over block sums (nb <= 1024)
__global__ void k_scan2(int* __restrict__ bsum, int nb) {
    __shared__ int sh[1024];
    int tid = threadIdx.x;
    int v = (tid < nb) ? bsum[tid] : 0;
    sh[tid] = v;
    __syncthreads();
    for (int o = 1; o < 1024; o <<= 1) {
        int t = (tid >= o) ? sh[tid - o] : 0;
        __syncthreads();
        sh[tid] += t;
        __syncthreads();
    }
    if (tid < nb) bsum[tid] = sh[tid] - v;  // exclusive block offset
}

// scan3: add block offsets; init cursor; set rowptr[N]=E
__global__ void k_scan3(int* __restrict__ rowptr, const int* __restrict__ bsum,
                        int* __restrict__ cursor, int N, int E) {
    int i = blockIdx.x * blockDim.x + threadIdx.x;
    if (i < N) {
        int r = rowptr[i] + bsum[i >> 8];
        rowptr[i] = r;
        cursor[i] = r;
    }
    if (i == 0) rowptr[N] = E;
}

// ---------------- counting-sort fill: CSR by destination ----------------
__global__ void k_fill(const int* __restrict__ edges, const float* __restrict__ dinv,
                       int* __restrict__ cursor, int* __restrict__ esrc,
                       float* __restrict__ ew, int E) {
    int e = blockIdx.x * blockDim.x + threadIdx.x;
    if (e >= E) return;
    int s = edges[e];
    int d = edges[E + e];
    float w = dinv[s] * dinv[d];
    int pos = atomicAdd(&cursor[d], 1);
    esrc[pos] = s;
    ew[pos] = w;
}

// ---------------- gather layer (pull), fused with out accumulation ----------
// 16 threads per node; thread c owns float4 chunk c of the 64-float row.
// xnext[node] = sum_{incoming e} w_e * xsrc[src_e]
// out[node]   = (first ? alpha0*emb[node] : out[node]) + alpha[aidx]*xnext[node]
__global__ void k_gather(const int* __restrict__ rowptr, const int* __restrict__ esrc,
                         const float* __restrict__ ew, const float* __restrict__ xsrc,
                         float* __restrict__ xnext, float* __restrict__ out,
                         const float* __restrict__ emb, const float* __restrict__ alpha,
                         int aidx, int first, int N) {
    int t = blockIdx.x * blockDim.x + threadIdx.x;
    int node = t >> 4, c = t & 15;
    if (node >= N) return;
    int beg = rowptr[node], end = rowptr[node + 1];
    float4 acc = make_float4(0.f, 0.f, 0.f, 0.f);
    for (int i = beg; i < end; ++i) {
        int s = esrc[i];
        float w = ew[i];
        float4 v = ((const float4*)(xsrc + (size_t)s * DIM))[c];
        acc.x += w * v.x; acc.y += w * v.y; acc.z += w * v.z; acc.w += w * v.w;
    }
    ((float4*)(xnext + (size_t)node * DIM))[c] = acc;

    float a = alpha[aidx];
    float4 o;
    if (first) {
        float a0 = alpha[0];
        float4 b = ((const float4*)(emb + (size_t)node * DIM))[c];
        o.x = a0 * b.x; o.y = a0 * b.y; o.z = a0 * b.z; o.w = a0 * b.w;
    } else {
        o = ((float4*)(out + (size_t)node * DIM))[c];
    }
    o.x += a * acc.x; o.y += a * acc.y; o.z += a * acc.z; o.w += a * acc.w;
    ((float4*)(out + (size_t)node * DIM))[c] = o;
}

// ---------------- final: res[e] = dot(out[src], out[dst]) ----------------
__global__ void k_final(const int* __restrict__ edges, const float* __restrict__ out,
                        float* __restrict__ res, int E) {
    int t = blockIdx.x * blockDim.x + threadIdx.x;
    int e = t >> 4, c = t & 15;
    if (e >= E) return;
    int s = edges[e];
    int d = edges[E + e];
    float4 a = ((const float4*)(out + (size_t)s * DIM))[c];
    float4 b = ((const float4*)(out + (size_t)d * DIM))[c];
    float p = a.x * b.x + a.y * b.y + a.z * b.z + a.w * b.w;
    p += __shfl_down(p, 8, 16);
    p += __shfl_down(p, 4, 16);
    p += __shfl_down(p, 2, 16);
    p += __shfl_down(p, 1, 16);
    if (c == 0) res[e] = p;
}

static inline size_t alignUp(size_t x) { return (x + 511) & ~size_t(511); }

extern "C" void kernel_launch(void* const* d_in, const int* in_sizes, int n_in,
                              void* d_out, int out_size, void* d_ws, size_t ws_size,
                              hipStream_t stream) {
    const void*  ei    = d_in[0];
    const float* emb   = (const float*)d_in[1];
    const float* alpha = (const float*)d_in[2];
    float*       res   = (float*)d_out;

    const int E = in_sizes[0] / 2;       // 1,000,000
    const int N = in_sizes[1] / DIM;     // 150,000
    const int NUM_LAYERS = 3;

    // ---- carve workspace ----
    char* w = (char*)d_ws;
    size_t off = 0;
    int*   edges  = (int*)(w + off);   off = alignUp(off + (size_t)2 * E * sizeof(int));
    int*   deg    = (int*)(w + off);   off = alignUp(off + (size_t)N * sizeof(int));      // reused as cursor
    float* dinv   = (float*)(w + off); off = alignUp(off + (size_t)N * sizeof(float));
    int*   rowptr = (int*)(w + off);   off = alignUp(off + (size_t)(N + 1) * sizeof(int));
    int*   bsum   = (int*)(w + off);   off = alignUp(off + (size_t)1024 * sizeof(int));
    int*   esrc   = (int*)(w + off);   off = alignUp(off + (size_t)E * sizeof(int));
    float* ew     = (float*)(w + off); off = alignUp(off + (size_t)E * sizeof(float));
    float* outv   = (float*)(w + off); off = alignUp(off + (size_t)N * DIM * sizeof(float));
    float* xA     = (float*)(w + off); off = alignUp(off + (size_t)N * DIM * sizeof(float));
    float* xB     = (float*)(w + off); off = alignUp(off + (size_t)N * DIM * sizeof(float));
    (void)ws_size;

    const int B = 256;
    const int n2 = 2 * E;
    const int nb = (N + 255) / 256;      // 586 <= 1024

    hipMemsetAsync(deg, 0, (size_t)N * sizeof(int), stream);
    k_convert<<<(n2 + B - 1) / B, B, 0, stream>>>(ei, edges, n2);
    k_deg<<<(E + B - 1) / B, B, 0, stream>>>(edges + E, deg, E);
    k_dinv<<<(N + B - 1) / B, B, 0, stream>>>(deg, dinv, N);

    k_scan1<<<nb, 256, 0, stream>>>(deg, rowptr, bsum, N);
    k_scan2<<<1, 1024, 0, stream>>>(bsum, nb);
    k_scan3<<<(N + B - 1) / B, B, 0, stream>>>(rowptr, bsum, deg /*cursor*/, N, E);

    k_fill<<<(E + B - 1) / B, B, 0, stream>>>(edges, dinv, deg /*cursor*/, esrc, ew, E);

    // ---- 3 gather layers, out-accumulation fused ----
    const float* xc = emb;
    float* bufs[2] = {xA, xB};
    long long tN = (long long)N * 16;
    int ggrid = (int)((tN + B - 1) / B);
    for (int i = 0; i < NUM_LAYERS; ++i) {
        float* xn = bufs[i & 1];
        k_gather<<<ggrid, B, 0, stream>>>(rowptr, esrc, ew, xc, xn, outv, emb, alpha,
                                          i + 1, (i == 0) ? 1 : 0, N);
        xc = xn;
    }

    long long t16 = (long long)E * 16;
    k_final<<<(int)((t16 + B - 1) / B), B, 0, stream>>>(edges, outv, res, E);
}

// Round 3
// 350.939 us; speedup vs baseline: 7.8225x; 1.0217x over previous
//
#include <hip/hip_runtime.h>

#define DIM 64

// ---------------- edge dtype detection + conversion + degree ----------------
__device__ __forceinline__ bool edges_are_i64(const unsigned int* w) {
    unsigned int acc = 0;
#pragma unroll
    for (int k = 0; k < 8; ++k) acc |= w[2 * k + 1];
    return acc == 0;
}

// converts edges to int32 AND accumulates dst degree (for i >= E)
__global__ void k_convert_deg(const void* ei_raw, int* edges, int* deg, int E) {
    int i = blockIdx.x * blockDim.x + threadIdx.x;
    int n2 = 2 * E;
    if (i >= n2) return;
    const unsigned int* w = (const unsigned int*)ei_raw;
    bool is64 = edges_are_i64(w);
    int v = is64 ? (int)(((const long long*)ei_raw)[i]) : ((const int*)ei_raw)[i];
    edges[i] = v;
    if (i >= E) atomicAdd(&deg[v], 1);  // v is a dst node id
}

// ---------------- exclusive scan of deg -> rowptr (+ fused dinv) ----------------
__global__ void k_scan1(const int* __restrict__ deg, int* __restrict__ rowptr,
                        int* __restrict__ bsum, float* __restrict__ dinv, int N) {
    __shared__ int sh[256];
    int i = blockIdx.x * 256 + threadIdx.x;
    int v = (i < N) ? deg[i] : 0;
    if (i < N) dinv[i] = v > 0 ? 1.0f / sqrtf((float)v) : 0.0f;
    sh[threadIdx.x] = v;
    __syncthreads();
    for (int o = 1; o < 256; o <<= 1) {
        int t = (threadIdx.x >= o) ? sh[threadIdx.x - o] : 0;
        __syncthreads();
        sh[threadIdx.x] += t;
        __syncthreads();
    }
    if (i < N) rowptr[i] = sh[threadIdx.x] - v;  // exclusive
    if (threadIdx.x == 255) bsum[blockIdx.x] = sh[255];
}

__global__ void k_scan2(int* __restrict__ bsum, int nb) {
    __shared__ int sh[1024];
    int tid = threadIdx.x;
    int v = (tid < nb) ? bsum[tid] : 0;
    sh[tid] = v;
    __syncthreads();
    for (int o = 1; o < 1024; o <<= 1) {
        int t = (tid >= o) ? sh[tid - o] : 0;
        __syncthreads();
        sh[tid] += t;
        __syncthreads();
    }
    if (tid < nb) bsum[tid] = sh[tid] - v;  // exclusive block offset
}

__global__ void k_scan3(int* __restrict__ rowptr, const int* __restrict__ bsum,
                        int* __restrict__ cursor, int N, int E) {
    int i = blockIdx.x * blockDim.x + threadIdx.x;
    if (i < N) {
        int r = rowptr[i] + bsum[i >> 8];
        rowptr[i] = r;
        cursor[i] = r;
    }
    if (i == 0) rowptr[N] = E;
}

// ---------------- counting-sort fill: CSR by destination (+ edge id) ----------
__global__ void k_fill(const int* __restrict__ edges, const float* __restrict__ dinv,
                       int* __restrict__ cursor, int* __restrict__ esrc,
                       float* __restrict__ ew, int* __restrict__ eidx, int E) {
    int e = blockIdx.x * blockDim.x + threadIdx.x;
    if (e >= E) return;
    int s = edges[e];
    int d = edges[E + e];
    float w = dinv[s] * dinv[d];
    int pos = atomicAdd(&cursor[d], 1);
    esrc[pos] = s;
    ew[pos] = w;
    eidx[pos] = e;
}

// ---------------- gather layer (pull), fused with out accumulation ----------
__global__ void k_gather(const int* __restrict__ rowptr, const int* __restrict__ esrc,
                         const float* __restrict__ ew, const float* __restrict__ xsrc,
                         float* __restrict__ xnext, float* __restrict__ out,
                         const float* __restrict__ emb, const float* __restrict__ alpha,
                         int aidx, int first, int N) {
    int t = blockIdx.x * blockDim.x + threadIdx.x;
    int node = t >> 4, c = t & 15;
    if (node >= N) return;
    int beg = rowptr[node], end = rowptr[node + 1];
    float4 acc = make_float4(0.f, 0.f, 0.f, 0.f);
    for (int i = beg; i < end; ++i) {
        int s = esrc[i];
        float w = ew[i];
        float4 v = ((const float4*)(xsrc + (size_t)s * DIM))[c];
        acc.x += w * v.x; acc.y += w * v.y; acc.z += w * v.z; acc.w += w * v.w;
    }
    ((float4*)(xnext + (size_t)node * DIM))[c] = acc;

    float a = alpha[aidx];
    float4 o;
    if (first) {
        float a0 = alpha[0];
        float4 b = ((const float4*)(emb + (size_t)node * DIM))[c];
        o.x = a0 * b.x; o.y = a0 * b.y; o.z = a0 * b.z; o.w = a0 * b.w;
    } else {
        o = ((float4*)(out + (size_t)node * DIM))[c];
    }
    o.x += a * acc.x; o.y += a * acc.y; o.z += a * acc.z; o.w += a * acc.w;
    ((float4*)(out + (size_t)node * DIM))[c] = o;
}

// ---------------- final via CSR: dst row kept in registers ----------------
// res[eidx[i]] = dot(out[dst], out[esrc[i]]) for i in [rowptr[d], rowptr[d+1])
__global__ void k_final_csr(const int* __restrict__ rowptr, const int* __restrict__ esrc,
                            const int* __restrict__ eidx, const float* __restrict__ out,
                            float* __restrict__ res, int N) {
    int t = blockIdx.x * blockDim.x + threadIdx.x;
    int node = t >> 4, c = t & 15;
    if (node >= N) return;
    int beg = rowptr[node], end = rowptr[node + 1];
    if (beg == end) return;
    float4 od = ((const float4*)(out + (size_t)node * DIM))[c];
    for (int i = beg; i < end; ++i) {
        int s = esrc[i];
        int eid = eidx[i];
        float4 a = ((const float4*)(out + (size_t)s * DIM))[c];
        float p = a.x * od.x + a.y * od.y + a.z * od.z + a.w * od.w;
        p += __shfl_down(p, 8, 16);
        p += __shfl_down(p, 4, 16);
        p += __shfl_down(p, 2, 16);
        p += __shfl_down(p, 1, 16);
        if (c == 0) res[eid] = p;
    }
}

static inline size_t alignUp(size_t x) { return (x + 511) & ~size_t(511); }

extern "C" void kernel_launch(void* const* d_in, const int* in_sizes, int n_in,
                              void* d_out, int out_size, void* d_ws, size_t ws_size,
                              hipStream_t stream) {
    const void*  ei    = d_in[0];
    const float* emb   = (const float*)d_in[1];
    const float* alpha = (const float*)d_in[2];
    float*       res   = (float*)d_out;

    const int E = in_sizes[0] / 2;       // 1,000,000
    const int N = in_sizes[1] / DIM;     // 150,000
    const int NUM_LAYERS = 3;

    // ---- carve workspace ----
    char* w = (char*)d_ws;
    size_t off = 0;
    int*   edges  = (int*)(w + off);   off = alignUp(off + (size_t)2 * E * sizeof(int));
    int*   deg    = (int*)(w + off);   off = alignUp(off + (size_t)N * sizeof(int));  // reused as cursor
    float* dinv   = (float*)(w + off); off = alignUp(off + (size_t)N * sizeof(float));
    int*   rowptr = (int*)(w + off);   off = alignUp(off + (size_t)(N + 1) * sizeof(int));
    int*   bsum   = (int*)(w + off);   off = alignUp(off + (size_t)1024 * sizeof(int));
    int*   esrc   = (int*)(w + off);   off = alignUp(off + (size_t)E * sizeof(int));
    float* ew     = (float*)(w + off); off = alignUp(off + (size_t)E * sizeof(float));
    int*   eidx   = (int*)(w + off);   off = alignUp(off + (size_t)E * sizeof(int));
    float* outv   = (float*)(w + off); off = alignUp(off + (size_t)N * DIM * sizeof(float));
    float* xA     = (float*)(w + off); off = alignUp(off + (size_t)N * DIM * sizeof(float));
    float* xB     = (float*)(w + off); off = alignUp(off + (size_t)N * DIM * sizeof(float));
    (void)ws_size;

    const int B = 256;
    const int n2 = 2 * E;
    const int nb = (N + 255) / 256;      // 586 <= 1024

    hipMemsetAsync(deg, 0, (size_t)N * sizeof(int), stream);
    k_convert_deg<<<(n2 + B - 1) / B, B, 0, stream>>>(ei, edges, deg, E);

    k_scan1<<<nb, 256, 0, stream>>>(deg, rowptr, bsum, dinv, N);
    k_scan2<<<1, 1024, 0, stream>>>(bsum, nb);
    k_scan3<<<(N + B - 1) / B, B, 0, stream>>>(rowptr, bsum, deg /*cursor*/, N, E);

    k_fill<<<(E + B - 1) / B, B, 0, stream>>>(edges, dinv, deg /*cursor*/, esrc, ew, eidx, E);

    // ---- 3 gather layers, out-accumulation fused ----
    const float* xc = emb;
    float* bufs[2] = {xA, xB};
    long long tN = (long long)N * 16;
    int ggrid = (int)((tN + B - 1) / B);
    for (int i = 0; i < NUM_LAYERS; ++i) {
        float* xn = bufs[i & 1];
        k_gather<<<ggrid, B, 0, stream>>>(rowptr, esrc, ew, xc, xn, outv, emb, alpha,
                                          i + 1, (i == 0) ? 1 : 0, N);
        xc = xn;
    }

    // ---- final dots in CSR order, scatter to original edge ids ----
    k_final_csr<<<ggrid, B, 0, stream>>>(rowptr, esrc, eidx, outv, res, N);
}

// Round 4
// 273.784 us; speedup vs baseline: 10.0270x; 1.2818x over previous
//
#include <hip/hip_runtime.h>
#include <hip/hip_fp16.h>

#define DIM 64

// ---------------- helpers: half2 <-> float punning ----------------
__device__ __forceinline__ float2 h2f(unsigned int u) {
    __half2 h = *reinterpret_cast<__half2*>(&u);
    return __half22float2(h);
}
__device__ __forceinline__ unsigned int f2h(float a, float b) {
    __half2 h = __floats2half2_rn(a, b);
    return *reinterpret_cast<unsigned int*>(&h);
}

// ---------------- edge dtype detection + conversion + degree ----------------
__device__ __forceinline__ bool edges_are_i64(const unsigned int* w) {
    unsigned int acc = 0;
#pragma unroll
    for (int k = 0; k < 8; ++k) acc |= w[2 * k + 1];
    return acc == 0;
}

__global__ void k_convert_deg(const void* ei_raw, int* edges, int* deg, int E) {
    int i = blockIdx.x * blockDim.x + threadIdx.x;
    int n2 = 2 * E;
    if (i >= n2) return;
    const unsigned int* w = (const unsigned int*)ei_raw;
    bool is64 = edges_are_i64(w);
    int v = is64 ? (int)(((const long long*)ei_raw)[i]) : ((const int*)ei_raw)[i];
    edges[i] = v;
    if (i >= E) atomicAdd(&deg[v], 1);  // dst degree
}

// ---------------- f32 -> f16 row conversion (8 elems / thread) --------------
__global__ void k_tohalf(const float* __restrict__ x, __half* __restrict__ xh, int n8) {
    int i = blockIdx.x * blockDim.x + threadIdx.x;
    if (i >= n8) return;
    const float4* p = (const float4*)(x + (size_t)i * 8);
    float4 a = p[0], b = p[1];
    uint4 o;
    o.x = f2h(a.x, a.y); o.y = f2h(a.z, a.w);
    o.z = f2h(b.x, b.y); o.w = f2h(b.z, b.w);
    ((uint4*)xh)[i] = o;
}

// ---------------- exclusive scan of deg -> rowptr (+ fused dinv) ------------
__global__ void k_scan1(const int* __restrict__ deg, int* __restrict__ rowptr,
                        int* __restrict__ bsum, float* __restrict__ dinv, int N) {
    __shared__ int sh[256];
    int i = blockIdx.x * 256 + threadIdx.x;
    int v = (i < N) ? deg[i] : 0;
    if (i < N) dinv[i] = v > 0 ? 1.0f / sqrtf((float)v) : 0.0f;
    sh[threadIdx.x] = v;
    __syncthreads();
    for (int o = 1; o < 256; o <<= 1) {
        int t = (threadIdx.x >= o) ? sh[threadIdx.x - o] : 0;
        __syncthreads();
        sh[threadIdx.x] += t;
        __syncthreads();
    }
    if (i < N) rowptr[i] = sh[threadIdx.x] - v;  // exclusive
    if (threadIdx.x == 255) bsum[blockIdx.x] = sh[255];
}

__global__ void k_scan2(int* __restrict__ bsum, int nb) {
    __shared__ int sh[1024];
    int tid = threadIdx.x;
    int v = (tid < nb) ? bsum[tid] : 0;
    sh[tid] = v;
    __syncthreads();
    for (int o = 1; o < 1024; o <<= 1) {
        int t = (tid >= o) ? sh[tid - o] : 0;
        __syncthreads();
        sh[tid] += t;
        __syncthreads();
    }
    if (tid < nb) bsum[tid] = sh[tid] - v;
}

__global__ void k_scan3(int* __restrict__ rowptr, const int* __restrict__ bsum,
                        int* __restrict__ cursor, int N, int E) {
    int i = blockIdx.x * blockDim.x + threadIdx.x;
    if (i < N) {
        int r = rowptr[i] + bsum[i >> 8];
        rowptr[i] = r;
        cursor[i] = r;
    }
    if (i == 0) rowptr[N] = E;
}

// ---------------- counting-sort fill: CSR by destination --------------------
__global__ void k_fill(const int* __restrict__ edges, const float* __restrict__ dinv,
                       int* __restrict__ cursor, int* __restrict__ esrc,
                       float* __restrict__ ew, int E) {
    int e = blockIdx.x * blockDim.x + threadIdx.x;
    if (e >= E) return;
    int s = edges[e];
    int d = edges[E + e];
    float w = dinv[s] * dinv[d];
    int pos = atomicAdd(&cursor[d], 1);
    esrc[pos] = s;
    ew[pos] = w;
}

// ---------------- gather layer (pull, fp16 features, fused accumulation) ----
// 8 lanes per node; lane c owns halves [8c, 8c+8) of the 64-wide row.
// xnext[node] = sum_e w_e * xsrc[src_e]        (f32 accum, stored f16)
// out handling: first -> out = a0*emb + a*acc (f32)
//               mid   -> out += a*acc          (f32)
//               last  -> outh = (f16)(out + a*acc), no xnext store
__global__ void k_gather_h(const int* __restrict__ rowptr, const int* __restrict__ esrc,
                           const float* __restrict__ ew, const __half* __restrict__ xsrc,
                           __half* __restrict__ xnext, float* __restrict__ out,
                           __half* __restrict__ outh, const float* __restrict__ emb,
                           const float* __restrict__ alpha, int aidx,
                           int first, int last, int N) {
    int t = blockIdx.x * blockDim.x + threadIdx.x;
    int node = t >> 3, c = t & 7;
    if (node >= N) return;
    int beg = rowptr[node], end = rowptr[node + 1];
    float acc[8] = {0.f, 0.f, 0.f, 0.f, 0.f, 0.f, 0.f, 0.f};
    for (int i = beg; i < end; ++i) {
        int s = esrc[i];
        float w = ew[i];
        uint4 u = ((const uint4*)(xsrc + (size_t)s * DIM))[c];
        float2 f0 = h2f(u.x), f1 = h2f(u.y), f2 = h2f(u.z), f3 = h2f(u.w);
        acc[0] += w * f0.x; acc[1] += w * f0.y;
        acc[2] += w * f1.x; acc[3] += w * f1.y;
        acc[4] += w * f2.x; acc[5] += w * f2.y;
        acc[6] += w * f3.x; acc[7] += w * f3.y;
    }
    if (!last) {
        uint4 o;
        o.x = f2h(acc[0], acc[1]); o.y = f2h(acc[2], acc[3]);
        o.z = f2h(acc[4], acc[5]); o.w = f2h(acc[6], acc[7]);
        ((uint4*)(xnext + (size_t)node * DIM))[c] = o;
    }

    float a = alpha[aidx];
    float o[8];
    if (first) {
        float a0 = alpha[0];
        const float4* ep = (const float4*)(emb + (size_t)node * DIM + c * 8);
        float4 e0 = ep[0], e1 = ep[1];
        o[0] = a0 * e0.x; o[1] = a0 * e0.y; o[2] = a0 * e0.z; o[3] = a0 * e0.w;
        o[4] = a0 * e1.x; o[5] = a0 * e1.y; o[6] = a0 * e1.z; o[7] = a0 * e1.w;
    } else {
        const float4* op = (const float4*)(out + (size_t)node * DIM + c * 8);
        float4 e0 = op[0], e1 = op[1];
        o[0] = e0.x; o[1] = e0.y; o[2] = e0.z; o[3] = e0.w;
        o[4] = e1.x; o[5] = e1.y; o[6] = e1.z; o[7] = e1.w;
    }
#pragma unroll
    for (int k = 0; k < 8; ++k) o[k] += a * acc[k];

    if (last) {
        uint4 u;
        u.x = f2h(o[0], o[1]); u.y = f2h(o[2], o[3]);
        u.z = f2h(o[4], o[5]); u.w = f2h(o[6], o[7]);
        ((uint4*)(outh + (size_t)node * DIM))[c] = u;
    } else {
        float4* op = (float4*)(out + (size_t)node * DIM + c * 8);
        op[0] = make_float4(o[0], o[1], o[2], o[3]);
        op[1] = make_float4(o[4], o[5], o[6], o[7]);
    }
}

// ---------------- final: res[e] = dot(outh[src], outh[dst]) -----------------
// 8 lanes per edge, original edge order (coalesced res writes).
__global__ void k_final_h(const int* __restrict__ edges, const __half* __restrict__ outh,
                          float* __restrict__ res, int E) {
    int t = blockIdx.x * blockDim.x + threadIdx.x;
    int e = t >> 3, c = t & 7;
    if (e >= E) return;
    int s = edges[e];
    int d = edges[E + e];
    uint4 ua = ((const uint4*)(outh + (size_t)s * DIM))[c];
    uint4 ub = ((const uint4*)(outh + (size_t)d * DIM))[c];
    float2 a0 = h2f(ua.x), a1 = h2f(ua.y), a2 = h2f(ua.z), a3 = h2f(ua.w);
    float2 b0 = h2f(ub.x), b1 = h2f(ub.y), b2 = h2f(ub.z), b3 = h2f(ub.w);
    float p = a0.x * b0.x + a0.y * b0.y + a1.x * b1.x + a1.y * b1.y +
              a2.x * b2.x + a2.y * b2.y + a3.x * b3.x + a3.y * b3.y;
    p += __shfl_down(p, 4, 8);
    p += __shfl_down(p, 2, 8);
    p += __shfl_down(p, 1, 8);
    if (c == 0) res[e] = p;
}

static inline size_t alignUp(size_t x) { return (x + 511) & ~size_t(511); }

extern "C" void kernel_launch(void* const* d_in, const int* in_sizes, int n_in,
                              void* d_out, int out_size, void* d_ws, size_t ws_size,
                              hipStream_t stream) {
    const void*  ei    = d_in[0];
    const float* emb   = (const float*)d_in[1];
    const float* alpha = (const float*)d_in[2];
    float*       res   = (float*)d_out;

    const int E = in_sizes[0] / 2;       // 1,000,000
    const int N = in_sizes[1] / DIM;     // 150,000
    const int NUM_LAYERS = 3;

    // ---- carve workspace ----
    char* w = (char*)d_ws;
    size_t off = 0;
    int*    edges  = (int*)(w + off);    off = alignUp(off + (size_t)2 * E * sizeof(int));
    int*    deg    = (int*)(w + off);    off = alignUp(off + (size_t)N * sizeof(int));  // -> cursor
    float*  dinv   = (float*)(w + off);  off = alignUp(off + (size_t)N * sizeof(float));
    int*    rowptr = (int*)(w + off);    off = alignUp(off + (size_t)(N + 1) * sizeof(int));
    int*    bsum   = (int*)(w + off);    off = alignUp(off + (size_t)1024 * sizeof(int));
    int*    esrc   = (int*)(w + off);    off = alignUp(off + (size_t)E * sizeof(int));
    float*  ew     = (float*)(w + off);  off = alignUp(off + (size_t)E * sizeof(float));
    float*  outv   = (float*)(w + off);  off = alignUp(off + (size_t)N * DIM * sizeof(float));
    __half* embh   = (__half*)(w + off); off = alignUp(off + (size_t)N * DIM * sizeof(__half));
    __half* xAh    = (__half*)(w + off); off = alignUp(off + (size_t)N * DIM * sizeof(__half));
    __half* xBh    = (__half*)(w + off); off = alignUp(off + (size_t)N * DIM * sizeof(__half));
    __half* outh   = (__half*)(w + off); off = alignUp(off + (size_t)N * DIM * sizeof(__half));
    (void)ws_size;

    const int B = 256;
    const int n2 = 2 * E;
    const int nb = (N + 255) / 256;      // 586 <= 1024
    const int n8 = N * DIM / 8;

    hipMemsetAsync(deg, 0, (size_t)N * sizeof(int), stream);
    k_convert_deg<<<(n2 + B - 1) / B, B, 0, stream>>>(ei, edges, deg, E);
    k_tohalf<<<(n8 + B - 1) / B, B, 0, stream>>>(emb, embh, n8);

    k_scan1<<<nb, 256, 0, stream>>>(deg, rowptr, bsum, dinv, N);
    k_scan2<<<1, 1024, 0, stream>>>(bsum, nb);
    k_scan3<<<(N + B - 1) / B, B, 0, stream>>>(rowptr, bsum, deg /*cursor*/, N, E);

    k_fill<<<(E + B - 1) / B, B, 0, stream>>>(edges, dinv, deg /*cursor*/, esrc, ew, E);

    // ---- 3 gather layers (fp16 features) ----
    long long tN8 = (long long)N * 8;
    int ggrid = (int)((tN8 + B - 1) / B);
    const __half* xc = embh;
    __half* bufs[2] = {xAh, xBh};
    for (int i = 0; i < NUM_LAYERS; ++i) {
        __half* xn = bufs[i & 1];
        int last = (i == NUM_LAYERS - 1) ? 1 : 0;
        k_gather_h<<<ggrid, B, 0, stream>>>(rowptr, esrc, ew, xc, xn, outv, outh,
                                            emb, alpha, i + 1, (i == 0) ? 1 : 0, last, N);
        xc = xn;
    }

    // ---- final dots, original edge order ----
    long long tE8 = (long long)E * 8;
    k_final_h<<<(int)((tE8 + B - 1) / B), B, 0, stream>>>(edges, outh, res, E);
}